// Round 8
// baseline (227.478 us; speedup 1.0000x reference)
//
#include <hip/hip_runtime.h>
#include <hip/hip_bf16.h>
#include <cmath>

#define T_DIM 512
#define N_DIM 512
#define M_DIM 256
#define B_DIM 256

typedef __bf16 bf16x8 __attribute__((ext_vector_type(8)));
typedef float  f32x4  __attribute__((ext_vector_type(4)));
typedef unsigned int u32;

#define WAITVM(N) asm volatile("s_waitcnt vmcnt(" #N ") lgkmcnt(0)" ::: "memory")
#define PHASE_BARRIER() do { __builtin_amdgcn_sched_barrier(0); \
                             __builtin_amdgcn_s_barrier();      \
                             __builtin_amdgcn_sched_barrier(0); } while (0)

__device__ __forceinline__ void gload16(const __bf16* g, __bf16* l) {
    __builtin_amdgcn_global_load_lds(
        (const __attribute__((address_space(1))) void*)g,
        (__attribute__((address_space(3))) void*)l, 16, 0, 0);
}

// ---------------- precompute: U_e -> bf16 ----------------
__global__ __launch_bounds__(256) void uconv_kernel(
    const float* __restrict__ U, __bf16* __restrict__ Uh)
{
    const int i = (blockIdx.x * 256 + threadIdx.x) * 2;
    float2 v = *(const float2*)(U + i);
    Uh[i]   = (__bf16)v.x;
    Uh[i+1] = (__bf16)v.y;
}

// ---------------- wq[b,t] = concat(h,s) . W_e[t,:] ----------------
__global__ __launch_bounds__(256) void wq_kernel(
    const float* __restrict__ h_t, const float* __restrict__ s_t,
    const float* __restrict__ W_e, float* __restrict__ wq)
{
    __shared__ float q[2 * M_DIM];
    const int b = blockIdx.x;
    const int tid = threadIdx.x;
    q[tid]         = h_t[(size_t)b * M_DIM + tid];
    q[M_DIM + tid] = s_t[(size_t)b * M_DIM + tid];
    __syncthreads();
    for (int tt = tid; tt < T_DIM; tt += 256) {
        const float4* wrow = (const float4*)(W_e + (size_t)tt * (2 * M_DIM));
        float acc = 0.f;
        #pragma unroll 4
        for (int k4 = 0; k4 < (2 * M_DIM) / 4; ++k4) {
            float4 w = wrow[k4];
            acc += q[4*k4+0] * w.x + q[4*k4+1] * w.y
                 + q[4*k4+2] * w.z + q[4*k4+3] * w.w;
        }
        wq[(size_t)b * T_DIM + tt] = acc;
    }
}

// ---------------- fused GEMM, 2-tile-deep pipeline ----------------
// B: 3-buffer LDS ring (gload_lds); A: f32 regs 2 sets deep, cvt+swizzled
// transpose write. Steady-state sync: vmcnt(8)+lgkmcnt(0)+raw s_barrier.
__global__ __launch_bounds__(256, 2) void fused6_kernel(
    const float* __restrict__ data, const __bf16* __restrict__ Uh,
    const float* __restrict__ v_e, const float* __restrict__ wq,
    float* __restrict__ partial)
{
    __shared__ __align__(16) __bf16 As[2][128 * 32];   // 16 KB
    __shared__ __align__(16) __bf16 Bs[3][256 * 32];   // 48 KB
    __shared__ float sc[128];

    // XCD-aware decode
    const int wg    = blockIdx.x;
    const int xcd   = wg & 7;
    const int local = wg >> 3;
    const int sh    = local & 1;
    const int p     = xcd + 8 * (local >> 1);
    const int b     = p >> 2;
    const int nb    = p & 3;

    const int tid  = threadIdx.x;
    const int lane = tid & 63;
    const int wid  = tid >> 6;
    const int wm   = wid >> 1;
    const int wn   = wid & 1;

    if (tid < 128) sc[tid] = 0.f;

    f32x4 acc[4][8];
    const f32x4 zero = {0.f, 0.f, 0.f, 0.f};
    #pragma unroll
    for (int i = 0; i < 4; ++i)
        #pragma unroll
        for (int j = 0; j < 8; ++j)
            acc[i][j] = zero;

    const float*  Ab = data + (size_t)b * T_DIM * N_DIM + nb * 128;
    const __bf16* Bb = Uh + (size_t)(sh * 256) * T_DIM;

    // A staging mapping (R5-proven): rp = t-pair, cg -> 8 n rows
    const int rp = tid >> 4;
    const int cg = tid & 15;
    const int n0 = cg * 8;

    // B staging
    const int r0 = tid >> 2;
    const int ce = (tid & 3) * 8;

    const int fr = lane & 15;
    const int kb = (lane >> 4) * 8;

    // fragment read offsets; A swizzle key(row) = ((row>>3)^(row>>1))&3 on elem bits 3-4
    int aoff[4];
    #pragma unroll
    for (int mi = 0; mi < 4; ++mi) {
        const int row = wm * 64 + mi * 16 + fr;
        const int key = ((row >> 3) ^ (row >> 1)) & 3;
        aoff[mi] = row * 32 + (kb ^ (key << 3));
    }
    int boff[8];
    #pragma unroll
    for (int ni = 0; ni < 8; ++ni)
        boff[ni] = (wn * 128 + ni * 16 + fr) * 32 + kb;

    float4 pl[4], paA[4], paB[4];

    // cvt + swizzled transpose-write of one pa set into an As buffer
    auto cvt_store = [&](const float4* s, __bf16* dst) {
        u32* A32 = (u32*)dst;
        const float lo_[8] = {s[0].x, s[0].y, s[0].z, s[0].w, s[1].x, s[1].y, s[1].z, s[1].w};
        const float hi_[8] = {s[2].x, s[2].y, s[2].z, s[2].w, s[3].x, s[3].y, s[3].z, s[3].w};
        #pragma unroll
        for (int j = 0; j < 8; ++j) {
            __bf16 l = (__bf16)lo_[j];
            __bf16 h = (__bf16)hi_[j];
            u32 w = ((u32)__builtin_bit_cast(unsigned short, h) << 16)
                  |  (u32)__builtin_bit_cast(unsigned short, l);
            const int key = (cg ^ (j >> 1)) & 3;           // == ((row>>3)^(row>>1))&3
            A32[(n0 + j) * 16 + (rp ^ (key << 2))] = w;
        }
    };
    auto load_pa = [&](float4* d, int t) {
        const float* src = Ab + (size_t)(32 * t + 2 * rp) * N_DIM + n0;
        d[0] = *(const float4*)src;
        d[1] = *(const float4*)(src + 4);
        d[2] = *(const float4*)(src + N_DIM);
        d[3] = *(const float4*)(src + N_DIM + 4);
    };
    auto stage_b = [&](int t, int buf) {
        #pragma unroll
        for (int i = 0; i < 4; ++i)
            gload16(Bb + (size_t)(i * 64 + r0) * T_DIM + 32 * t + ce,
                    &Bs[buf][tid * 8] + i * 64 * 32);
    };

    // ---- prologue: tile0 direct, B(0),B(1) staged, paA<-tile1, paB<-tile2
    load_pa(pl, 0);
    stage_b(0, 0);
    stage_b(1, 1);
    load_pa(paA, 1);
    load_pa(paB, 2);
    cvt_store(pl, As[0]);     // compiler auto-waits vmcnt for pl only
    WAITVM(12);               // retire B(0) (+pl); leave B(1), paA, paB in flight
    PHASE_BARRIER();

    // ---- main loop, fully unrolled; steady wait vmcnt(8)
    #pragma unroll
    for (int k = 0; k < 16; ++k) {
        const int cb = k & 1;
        const int bb = k % 3;

        bf16x8 a[4], bv[8];
        #pragma unroll
        for (int mi = 0; mi < 4; ++mi)
            a[mi] = *(const bf16x8*)&As[cb][aoff[mi]];
        #pragma unroll
        for (int ni = 0; ni < 8; ++ni)
            bv[ni] = *(const bf16x8*)&Bs[bb][boff[ni]];

        if (k <= 13) stage_b(k + 2, (k + 2) % 3);
        if (k <= 14) {
            if ((k & 1) == 0) cvt_store(paA, As[cb ^ 1]);
            else              cvt_store(paB, As[cb ^ 1]);
        }
        if (k <= 12) {
            if ((k & 1) == 0) load_pa(paA, k + 3);
            else              load_pa(paB, k + 3);
        }

        __builtin_amdgcn_s_setprio(1);
        #pragma unroll
        for (int mi = 0; mi < 4; ++mi)
            #pragma unroll
            for (int ni = 0; ni < 8; ++ni)
                acc[mi][ni] = __builtin_amdgcn_mfma_f32_16x16x32_bf16(a[mi], bv[ni], acc[mi][ni], 0, 0, 0);
        __builtin_amdgcn_s_setprio(0);

        if (k <= 12)      { WAITVM(8); }
        else if (k == 13) { WAITVM(4); }
        else if (k == 14) { WAITVM(0); }
        if (k <= 14) PHASE_BARRIER();
    }

    // ---- epilogue: tanh + v-weighted reduce over this wave's 128 s-columns
    float wqv[8], vev[8];
    #pragma unroll
    for (int ni = 0; ni < 8; ++ni) {
        const int scol = sh * 256 + wn * 128 + ni * 16 + fr;
        wqv[ni] = wq[(size_t)b * T_DIM + scol];
        vev[ni] = v_e[scol];
    }
    const int g = lane >> 4;
    #pragma unroll
    for (int mi = 0; mi < 4; ++mi) {
        #pragma unroll
        for (int rg = 0; rg < 4; ++rg) {
            float part = 0.f;
            #pragma unroll
            for (int ni = 0; ni < 8; ++ni)
                part += vev[ni] * tanhf(wqv[ni] + acc[mi][ni][rg]);
            part += __shfl_xor(part, 1);
            part += __shfl_xor(part, 2);
            part += __shfl_xor(part, 4);
            part += __shfl_xor(part, 8);
            if (fr == 0)
                atomicAdd(&sc[wm * 64 + mi * 16 + 4 * g + rg], part);
            // exactly 2 adds per slot (wn=0,1): f32 add commutative -> deterministic
        }
    }
    __syncthreads();
    if (tid < 128)
        partial[((size_t)b * 2 + sh) * N_DIM + nb * 128 + tid] = sc[tid];
}

// ---------------- softmax over n (sums the 2 s-half partials) ----------------
__global__ __launch_bounds__(512) void softmax_kernel(
    const float* __restrict__ partial, float* __restrict__ out)
{
    const int b = blockIdx.x;
    const int n = threadIdx.x;
    const float* p = partial + (size_t)b * 2 * N_DIM;
    float s = p[n] + p[N_DIM + n];

    float m = s;
    #pragma unroll
    for (int off = 1; off < 64; off <<= 1)
        m = fmaxf(m, __shfl_xor(m, off));
    __shared__ float red[8];
    const int wv = n >> 6;
    if ((n & 63) == 0) red[wv] = m;
    __syncthreads();
    float bm = red[0];
    #pragma unroll
    for (int i = 1; i < 8; ++i) bm = fmaxf(bm, red[i]);

    float e = expf(s - bm);
    float t = e;
    #pragma unroll
    for (int off = 1; off < 64; off <<= 1)
        t += __shfl_xor(t, off);
    __syncthreads();
    if ((n & 63) == 0) red[wv] = t;
    __syncthreads();
    float tot = 0.f;
    #pragma unroll
    for (int i = 0; i < 8; ++i) tot += red[i];

    out[(size_t)b * N_DIM + n] = e / tot;
}

extern "C" void kernel_launch(void* const* d_in, const int* in_sizes, int n_in,
                              void* d_out, int out_size, void* d_ws, size_t ws_size,
                              hipStream_t stream) {
    const float* h_t  = (const float*)d_in[0];
    const float* s_t  = (const float*)d_in[1];
    const float* data = (const float*)d_in[2];
    const float* W_e  = (const float*)d_in[3];
    const float* U_e  = (const float*)d_in[4];
    const float* v_e  = (const float*)d_in[5];
    float* out = (float*)d_out;

    const size_t wq_elems      = (size_t)B_DIM * T_DIM;         // f32
    const size_t partial_elems = (size_t)B_DIM * 2 * N_DIM;     // f32
    const size_t u_elems       = (size_t)T_DIM * T_DIM;         // bf16

    float* wq      = (float*)d_ws;
    float* partial = wq + wq_elems;
    __bf16* Uh     = (__bf16*)(partial + partial_elems);

    wq_kernel<<<B_DIM, 256, 0, stream>>>(h_t, s_t, W_e, wq);
    uconv_kernel<<<(int)(u_elems / 512), 256, 0, stream>>>(U_e, Uh);
    fused6_kernel<<<B_DIM * 8, 256, 0, stream>>>(data, Uh, v_e, wq, partial);
    softmax_kernel<<<B_DIM, 512, 0, stream>>>(partial, out);
}

// Round 9
// 175.673 us; speedup vs baseline: 1.2949x; 1.2949x over previous
//
#include <hip/hip_runtime.h>
#include <hip/hip_bf16.h>
#include <cmath>

#define T_DIM 512
#define N_DIM 512
#define M_DIM 256
#define B_DIM 256

typedef __bf16 bf16x8 __attribute__((ext_vector_type(8)));
typedef float  f32x4  __attribute__((ext_vector_type(4)));
typedef unsigned int u32;

__device__ __forceinline__ void gload16(const __bf16* g, __bf16* l) {
    __builtin_amdgcn_global_load_lds(
        (const __attribute__((address_space(1))) void*)g,
        (__attribute__((address_space(3))) void*)l, 16, 0, 0);
}

// bank-spread key: maps 16 consecutive rows onto all 8 16B bank-groups
__device__ __forceinline__ int bkey(int r) { return ((r >> 3) ^ (r >> 1)) & 3; }

// ---------------- precompute: U_e -> bf16 ----------------
__global__ __launch_bounds__(256) void uconv_kernel(
    const float* __restrict__ U, __bf16* __restrict__ Uh)
{
    const int i = (blockIdx.x * 256 + threadIdx.x) * 2;
    float2 v = *(const float2*)(U + i);
    Uh[i]   = (__bf16)v.x;
    Uh[i+1] = (__bf16)v.y;
}

// ---------------- wq[b,t] = concat(h,s) . W_e[t,:] ----------------
__global__ __launch_bounds__(256) void wq_kernel(
    const float* __restrict__ h_t, const float* __restrict__ s_t,
    const float* __restrict__ W_e, float* __restrict__ wq)
{
    __shared__ float q[2 * M_DIM];
    const int b = blockIdx.x;
    const int tid = threadIdx.x;
    q[tid]         = h_t[(size_t)b * M_DIM + tid];
    q[M_DIM + tid] = s_t[(size_t)b * M_DIM + tid];
    __syncthreads();
    for (int tt = tid; tt < T_DIM; tt += 256) {
        const float4* wrow = (const float4*)(W_e + (size_t)tt * (2 * M_DIM));
        float acc = 0.f;
        #pragma unroll 4
        for (int k4 = 0; k4 < (2 * M_DIM) / 4; ++k4) {
            float4 w = wrow[k4];
            acc += q[4*k4+0] * w.x + q[4*k4+1] * w.y
                 + q[4*k4+2] * w.z + q[4*k4+3] * w.w;
        }
        wq[(size_t)b * T_DIM + tt] = acc;
    }
}

// ---------------- fused: in-kernel A-transpose + GEMM + tanh + v-dot ----------------
// R6 structure (dbuf, one __syncthreads per K-step) + full bank-conflict fix:
// B staged via global_load_lds with SOURCE-side chunk swizzle (linear LDS dest),
// read back with matching XOR -> 8-way conflict becomes ~2-way (free).
// A transpose-write/read swizzled with the same key function.
__global__ __launch_bounds__(256, 2) void fused7_kernel(
    const float* __restrict__ data, const __bf16* __restrict__ Uh,
    const float* __restrict__ v_e, const float* __restrict__ wq,
    float* __restrict__ partial)
{
    __shared__ __align__(16) __bf16 As[2][128 * 32];   // [n][t], swizzled chunks
    __shared__ __align__(16) __bf16 Bs[2][256 * 32];   // [s][t], source-swizzled chunks
    __shared__ float sc[128];

    // XCD-aware decode: both sh-halves of a (b,nb) pair land on the same XCD.
    const int wg    = blockIdx.x;
    const int xcd   = wg & 7;
    const int local = wg >> 3;
    const int sh    = local & 1;
    const int p     = xcd + 8 * (local >> 1);   // bijective over [0,1024)
    const int b     = p >> 2;
    const int nb    = p & 3;

    const int tid  = threadIdx.x;
    const int lane = tid & 63;
    const int wid  = tid >> 6;
    const int wm   = wid >> 1;           // n-half
    const int wn   = wid & 1;            // s-half

    if (tid < 128) sc[tid] = 0.f;

    f32x4 acc[4][8];
    const f32x4 zero = {0.f, 0.f, 0.f, 0.f};
    #pragma unroll
    for (int i = 0; i < 4; ++i)
        #pragma unroll
        for (int j = 0; j < 8; ++j)
            acc[i][j] = zero;

    const float*  Ab = data + (size_t)b * T_DIM * N_DIM + nb * 128;
    const __bf16* Bb = Uh + (size_t)(sh * 256) * T_DIM;

    // A staging: rp = t-pair row, cg = n col-group; 16 lanes = 512 contiguous bytes.
    const int rp = tid >> 4;
    const int cg = tid & 15;
    const int n0 = cg * 8;

    // B staging: 4 x gload_lds; LDS dest linear (tid*8), global chunk pre-swizzled
    const int r0   = tid >> 2;
    const int keyB = bkey(r0);                    // invariant across i*64 row offsets
    const int ce   = (((tid & 3) ^ keyB) * 8);    // swizzled global chunk offset

    const int fr = lane & 15;
    const int kb = (lane >> 4) * 8;

    // fragment read offsets, both operands swizzled with bkey(row)
    int aoff[4];
    #pragma unroll
    for (int mi = 0; mi < 4; ++mi) {
        const int row = wm * 64 + mi * 16 + fr;
        aoff[mi] = row * 32 + (kb ^ (bkey(row) << 3));
    }
    int boff[8];
    #pragma unroll
    for (int ni = 0; ni < 8; ++ni) {
        const int row = wn * 128 + ni * 16 + fr;
        boff[ni] = row * 32 + (kb ^ (bkey(row) << 3));
    }

    // ---- prologue: stage tile 0 into buf 0, prefetch A regs for tile 1
    const float* s0 = Ab + (size_t)(2 * rp) * N_DIM + n0;
    float4 pa0 = *(const float4*)s0;
    float4 pa1 = *(const float4*)(s0 + 4);
    float4 pa2 = *(const float4*)(s0 + N_DIM);
    float4 pa3 = *(const float4*)(s0 + N_DIM + 4);

    #pragma unroll
    for (int i = 0; i < 4; ++i)
        gload16(Bb + (size_t)(i * 64 + r0) * T_DIM + ce, &Bs[0][tid * 8] + i * 64 * 32);
    {
        u32* As32 = (u32*)As[0];
        const float lo_[8] = {pa0.x, pa0.y, pa0.z, pa0.w, pa1.x, pa1.y, pa1.z, pa1.w};
        const float hi_[8] = {pa2.x, pa2.y, pa2.z, pa2.w, pa3.x, pa3.y, pa3.z, pa3.w};
        #pragma unroll
        for (int j = 0; j < 8; ++j) {
            __bf16 l = (__bf16)lo_[j];
            __bf16 h = (__bf16)hi_[j];
            u32 w = ((u32)__builtin_bit_cast(unsigned short, h) << 16)
                  |  (u32)__builtin_bit_cast(unsigned short, l);
            const int key = (cg ^ (j >> 1)) & 3;          // == bkey(n0+j)
            As32[(n0 + j) * 16 + (rp ^ (key << 2))] = w;
        }
    }
    {
        const float* sn = Ab + (size_t)(32 + 2 * rp) * N_DIM + n0;
        pa0 = *(const float4*)sn;
        pa1 = *(const float4*)(sn + 4);
        pa2 = *(const float4*)(sn + N_DIM);
        pa3 = *(const float4*)(sn + N_DIM + 4);
    }
    __syncthreads();

    int cur = 0;
    for (int k0 = 0; k0 < T_DIM; k0 += 32) {
        // ---- fragment reads from buf[cur] FIRST (MFMA waits only on these)
        bf16x8 a[4], bv[8];
        #pragma unroll
        for (int mi = 0; mi < 4; ++mi)
            a[mi] = *(const bf16x8*)&As[cur][aoff[mi]];
        #pragma unroll
        for (int ni = 0; ni < 8; ++ni)
            bv[ni] = *(const bf16x8*)&Bs[cur][boff[ni]];

        // ---- stage tile k+1 into buf[cur^1] (overlaps with MFMA below)
        if (k0 + 32 < T_DIM) {
            const int nxt = cur ^ 1;
            #pragma unroll
            for (int i = 0; i < 4; ++i)
                gload16(Bb + (size_t)(i * 64 + r0) * T_DIM + (k0 + 32) + ce,
                        &Bs[nxt][tid * 8] + i * 64 * 32);
            u32* As32 = (u32*)As[nxt];
            const float lo_[8] = {pa0.x, pa0.y, pa0.z, pa0.w, pa1.x, pa1.y, pa1.z, pa1.w};
            const float hi_[8] = {pa2.x, pa2.y, pa2.z, pa2.w, pa3.x, pa3.y, pa3.z, pa3.w};
            #pragma unroll
            for (int j = 0; j < 8; ++j) {
                __bf16 l = (__bf16)lo_[j];
                __bf16 h = (__bf16)hi_[j];
                u32 w = ((u32)__builtin_bit_cast(unsigned short, h) << 16)
                      |  (u32)__builtin_bit_cast(unsigned short, l);
                const int key = (cg ^ (j >> 1)) & 3;
                As32[(n0 + j) * 16 + (rp ^ (key << 2))] = w;
            }
            if (k0 + 64 < T_DIM) {
                const float* sn = Ab + (size_t)(k0 + 64 + 2 * rp) * N_DIM + n0;
                pa0 = *(const float4*)sn;
                pa1 = *(const float4*)(sn + 4);
                pa2 = *(const float4*)(sn + N_DIM);
                pa3 = *(const float4*)(sn + N_DIM + 4);
            }
        }

        // ---- MFMA on tile k
        __builtin_amdgcn_s_setprio(1);
        #pragma unroll
        for (int mi = 0; mi < 4; ++mi)
            #pragma unroll
            for (int ni = 0; ni < 8; ++ni)
                acc[mi][ni] = __builtin_amdgcn_mfma_f32_16x16x32_bf16(a[mi], bv[ni], acc[mi][ni], 0, 0, 0);
        __builtin_amdgcn_s_setprio(0);

        __syncthreads();   // drains stage ops; buf[cur^1] ready for next iter
        cur ^= 1;
    }

    // ---- epilogue: tanh + v-weighted reduce over this wave's 128 s-columns
    float wqv[8], vev[8];
    #pragma unroll
    for (int ni = 0; ni < 8; ++ni) {
        const int scol = sh * 256 + wn * 128 + ni * 16 + fr;
        wqv[ni] = wq[(size_t)b * T_DIM + scol];
        vev[ni] = v_e[scol];
    }
    const int g = lane >> 4;
    #pragma unroll
    for (int mi = 0; mi < 4; ++mi) {
        #pragma unroll
        for (int rg = 0; rg < 4; ++rg) {
            float part = 0.f;
            #pragma unroll
            for (int ni = 0; ni < 8; ++ni)
                part += vev[ni] * tanhf(wqv[ni] + acc[mi][ni][rg]);
            part += __shfl_xor(part, 1);
            part += __shfl_xor(part, 2);
            part += __shfl_xor(part, 4);
            part += __shfl_xor(part, 8);
            if (fr == 0)
                atomicAdd(&sc[wm * 64 + mi * 16 + 4 * g + rg], part);
            // exactly 2 adds per slot (wn=0,1): f32 add commutative -> deterministic
        }
    }
    __syncthreads();
    if (tid < 128)
        partial[((size_t)b * 2 + sh) * N_DIM + nb * 128 + tid] = sc[tid];
}

// ---------------- softmax over n (sums the 2 s-half partials) ----------------
__global__ __launch_bounds__(512) void softmax_kernel(
    const float* __restrict__ partial, float* __restrict__ out)
{
    const int b = blockIdx.x;
    const int n = threadIdx.x;
    const float* p = partial + (size_t)b * 2 * N_DIM;
    float s = p[n] + p[N_DIM + n];

    float m = s;
    #pragma unroll
    for (int off = 1; off < 64; off <<= 1)
        m = fmaxf(m, __shfl_xor(m, off));
    __shared__ float red[8];
    const int wv = n >> 6;
    if ((n & 63) == 0) red[wv] = m;
    __syncthreads();
    float bm = red[0];
    #pragma unroll
    for (int i = 1; i < 8; ++i) bm = fmaxf(bm, red[i]);

    float e = expf(s - bm);
    float t = e;
    #pragma unroll
    for (int off = 1; off < 64; off <<= 1)
        t += __shfl_xor(t, off);
    __syncthreads();
    if ((n & 63) == 0) red[wv] = t;
    __syncthreads();
    float tot = 0.f;
    #pragma unroll
    for (int i = 0; i < 8; ++i) tot += red[i];

    out[(size_t)b * N_DIM + n] = e / tot;
}

extern "C" void kernel_launch(void* const* d_in, const int* in_sizes, int n_in,
                              void* d_out, int out_size, void* d_ws, size_t ws_size,
                              hipStream_t stream) {
    const float* h_t  = (const float*)d_in[0];
    const float* s_t  = (const float*)d_in[1];
    const float* data = (const float*)d_in[2];
    const float* W_e  = (const float*)d_in[3];
    const float* U_e  = (const float*)d_in[4];
    const float* v_e  = (const float*)d_in[5];
    float* out = (float*)d_out;

    const size_t wq_elems      = (size_t)B_DIM * T_DIM;         // f32
    const size_t partial_elems = (size_t)B_DIM * 2 * N_DIM;     // f32
    const size_t u_elems       = (size_t)T_DIM * T_DIM;         // bf16

    float* wq      = (float*)d_ws;
    float* partial = wq + wq_elems;
    __bf16* Uh     = (__bf16*)(partial + partial_elems);

    wq_kernel<<<B_DIM, 256, 0, stream>>>(h_t, s_t, W_e, wq);
    uconv_kernel<<<(int)(u_elems / 512), 256, 0, stream>>>(U_e, Uh);
    fused7_kernel<<<B_DIM * 8, 256, 0, stream>>>(data, Uh, v_e, wq, partial);
    softmax_kernel<<<B_DIM, 512, 0, stream>>>(partial, out);
}

// Round 10
// 164.672 us; speedup vs baseline: 1.3814x; 1.0668x over previous
//
#include <hip/hip_runtime.h>
#include <hip/hip_bf16.h>
#include <cmath>

#define T_DIM 512
#define N_DIM 512
#define M_DIM 256
#define B_DIM 256

typedef __bf16 bf16x8 __attribute__((ext_vector_type(8)));
typedef float  f32x4  __attribute__((ext_vector_type(4)));
typedef unsigned int u32;

__device__ __forceinline__ void gload16(const __bf16* g, __bf16* l) {
    __builtin_amdgcn_global_load_lds(
        (const __attribute__((address_space(1))) void*)g,
        (__attribute__((address_space(3))) void*)l, 16, 0, 0);
}

// bank-spread key (kept from R9; correctness-verified)
__device__ __forceinline__ int bkey(int r) { return ((r >> 3) ^ (r >> 1)) & 3; }

// fast tanh: 1 - 2/(e^{2x}+1); exact at +-inf, ~1e-6 abs error
__device__ __forceinline__ float ftanh(float x) {
    return 1.f - 2.f / (__expf(2.f * x) + 1.f);
}

// ---------------- precompute: U_e -> bf16 ----------------
__global__ __launch_bounds__(256) void uconv_kernel(
    const float* __restrict__ U, __bf16* __restrict__ Uh)
{
    const int i = (blockIdx.x * 256 + threadIdx.x) * 2;
    float2 v = *(const float2*)(U + i);
    Uh[i]   = (__bf16)v.x;
    Uh[i+1] = (__bf16)v.y;
}

// ---------------- wq[b,t] = concat(h,s) . W_e[t,:] ----------------
__global__ __launch_bounds__(256) void wq_kernel(
    const float* __restrict__ h_t, const float* __restrict__ s_t,
    const float* __restrict__ W_e, float* __restrict__ wq)
{
    __shared__ float q[2 * M_DIM];
    const int b = blockIdx.x;
    const int tid = threadIdx.x;
    q[tid]         = h_t[(size_t)b * M_DIM + tid];
    q[M_DIM + tid] = s_t[(size_t)b * M_DIM + tid];
    __syncthreads();
    for (int tt = tid; tt < T_DIM; tt += 256) {
        const float4* wrow = (const float4*)(W_e + (size_t)tt * (2 * M_DIM));
        float acc = 0.f;
        #pragma unroll 4
        for (int k4 = 0; k4 < (2 * M_DIM) / 4; ++k4) {
            float4 w = wrow[k4];
            acc += q[4*k4+0] * w.x + q[4*k4+1] * w.y
                 + q[4*k4+2] * w.z + q[4*k4+3] * w.w;
        }
        wq[(size_t)b * T_DIM + tt] = acc;
    }
}

// ---------------- fused: 4 panels per wg, flat 64-step K-stream ----------------
// wg owns (sh, nb, bgrp); processes batches b = bgrp*4+0..3 back-to-back.
// A-stream is contiguous across panels (row = 32*t); B (U half) identical
// every panel -> L2-hot. One prologue/drain per wg instead of four.
__global__ __launch_bounds__(256, 2) void fused8_kernel(
    const float* __restrict__ data, const __bf16* __restrict__ Uh,
    const float* __restrict__ v_e, const float* __restrict__ wq,
    float* __restrict__ partial)
{
    __shared__ __align__(16) __bf16 As[2][128 * 32];
    __shared__ __align__(16) __bf16 Bs[2][256 * 32];
    __shared__ float sc[128];

    // decode 512 wgs: sh-pairs of same (bgrp,nb) share an XCD
    const int wg    = blockIdx.x;
    const int xcd   = wg & 7;
    const int local = wg >> 3;           // 0..63
    const int sh    = local & 1;
    const int q     = xcd + 8 * (local >> 1);   // 0..255, bijective
    const int bgrp  = q >> 2;            // 0..63
    const int nb    = q & 3;

    const int tid  = threadIdx.x;
    const int lane = tid & 63;
    const int wid  = tid >> 6;
    const int wm   = wid >> 1;
    const int wn   = wid & 1;

    if (tid < 128) sc[tid] = 0.f;

    f32x4 acc[4][8];
    const f32x4 zero = {0.f, 0.f, 0.f, 0.f};
    #pragma unroll
    for (int i = 0; i < 4; ++i)
        #pragma unroll
        for (int j = 0; j < 8; ++j)
            acc[i][j] = zero;

    // A staging map (R5-proven): rp = t-pair, cg -> 8 n rows, coalesced
    const int rp = tid >> 4;
    const int cg = tid & 15;
    const int n0 = cg * 8;

    // A per-tile source: row = 32*t + 2*rp (panels contiguous since 16*32=512)
    const float* Apan = data + ((size_t)bgrp * 4 * T_DIM) * N_DIM + nb * 128 + n0;

    // B staging: source-side chunk swizzle, linear LDS dest (R9)
    const __bf16* Bb = Uh + (size_t)(sh * 256) * T_DIM;
    const int r0   = tid >> 2;
    const int keyB = bkey(r0);
    const int ce   = (((tid & 3) ^ keyB) * 8);

    const int fr = lane & 15;
    const int kb = (lane >> 4) * 8;

    int aoff[4];
    #pragma unroll
    for (int mi = 0; mi < 4; ++mi) {
        const int row = wm * 64 + mi * 16 + fr;
        aoff[mi] = row * 32 + (kb ^ (bkey(row) << 3));
    }
    int boff[8];
    #pragma unroll
    for (int ni = 0; ni < 8; ++ni) {
        const int row = wn * 128 + ni * 16 + fr;
        boff[ni] = row * 32 + (kb ^ (bkey(row) << 3));
    }

    // epilogue constants (v_e is panel-invariant; wq is per-panel)
    float vev[8];
    #pragma unroll
    for (int ni = 0; ni < 8; ++ni)
        vev[ni] = v_e[sh * 256 + wn * 128 + ni * 16 + fr];
    const int g = lane >> 4;

    // ---- prologue: tile 0 -> buf 0; pa <- tile 1
    float4 pa0, pa1, pa2, pa3;
    {
        const float* s0 = Apan + (size_t)(2 * rp) * N_DIM;
        pa0 = *(const float4*)s0;
        pa1 = *(const float4*)(s0 + 4);
        pa2 = *(const float4*)(s0 + N_DIM);
        pa3 = *(const float4*)(s0 + N_DIM + 4);
    }
    #pragma unroll
    for (int i = 0; i < 4; ++i)
        gload16(Bb + (size_t)(i * 64 + r0) * T_DIM + ce, &Bs[0][tid * 8] + i * 64 * 32);
    {
        u32* As32 = (u32*)As[0];
        const float lo_[8] = {pa0.x, pa0.y, pa0.z, pa0.w, pa1.x, pa1.y, pa1.z, pa1.w};
        const float hi_[8] = {pa2.x, pa2.y, pa2.z, pa2.w, pa3.x, pa3.y, pa3.z, pa3.w};
        #pragma unroll
        for (int j = 0; j < 8; ++j) {
            __bf16 l = (__bf16)lo_[j];
            __bf16 h = (__bf16)hi_[j];
            u32 w = ((u32)__builtin_bit_cast(unsigned short, h) << 16)
                  |  (u32)__builtin_bit_cast(unsigned short, l);
            const int key = (cg ^ (j >> 1)) & 3;          // == bkey(n0+j)
            As32[(n0 + j) * 16 + (rp ^ (key << 2))] = w;
        }
    }
    {
        const float* sn = Apan + (size_t)(32 + 2 * rp) * N_DIM;
        pa0 = *(const float4*)sn;
        pa1 = *(const float4*)(sn + 4);
        pa2 = *(const float4*)(sn + N_DIM);
        pa3 = *(const float4*)(sn + N_DIM + 4);
    }
    __syncthreads();

    // ---- flat 64-step loop (4 panels x 16 K-steps)
    for (int t = 0; t < 64; ++t) {
        const int cur = t & 1;

        bf16x8 a[4], bv[8];
        #pragma unroll
        for (int mi = 0; mi < 4; ++mi)
            a[mi] = *(const bf16x8*)&As[cur][aoff[mi]];
        #pragma unroll
        for (int ni = 0; ni < 8; ++ni)
            bv[ni] = *(const bf16x8*)&Bs[cur][boff[ni]];

        if (t < 63) {
            const int nxt = cur ^ 1;
            const int kcol = ((t + 1) & 15) << 5;   // B wraps every panel
            #pragma unroll
            for (int i = 0; i < 4; ++i)
                gload16(Bb + (size_t)(i * 64 + r0) * T_DIM + kcol + ce,
                        &Bs[nxt][tid * 8] + i * 64 * 32);
            u32* As32 = (u32*)As[nxt];
            const float lo_[8] = {pa0.x, pa0.y, pa0.z, pa0.w, pa1.x, pa1.y, pa1.z, pa1.w};
            const float hi_[8] = {pa2.x, pa2.y, pa2.z, pa2.w, pa3.x, pa3.y, pa3.z, pa3.w};
            #pragma unroll
            for (int j = 0; j < 8; ++j) {
                __bf16 l = (__bf16)lo_[j];
                __bf16 h = (__bf16)hi_[j];
                u32 w = ((u32)__builtin_bit_cast(unsigned short, h) << 16)
                      |  (u32)__builtin_bit_cast(unsigned short, l);
                const int key = (cg ^ (j >> 1)) & 3;
                As32[(n0 + j) * 16 + (rp ^ (key << 2))] = w;
            }
            if (t < 62) {
                const float* sn = Apan + (size_t)(32 * (t + 2) + 2 * rp) * N_DIM;
                pa0 = *(const float4*)sn;
                pa1 = *(const float4*)(sn + 4);
                pa2 = *(const float4*)(sn + N_DIM);
                pa3 = *(const float4*)(sn + N_DIM + 4);
            }
        }

        __builtin_amdgcn_s_setprio(1);
        #pragma unroll
        for (int mi = 0; mi < 4; ++mi)
            #pragma unroll
            for (int ni = 0; ni < 8; ++ni)
                acc[mi][ni] = __builtin_amdgcn_mfma_f32_16x16x32_bf16(a[mi], bv[ni], acc[mi][ni], 0, 0, 0);
        __builtin_amdgcn_s_setprio(0);

        __syncthreads();   // buf[cur^1] ready for next step

        // ---- per-panel epilogue (uniform branch)
        if ((t & 15) == 15) {
            const int b = bgrp * 4 + (t >> 4);
            float wqv[8];
            #pragma unroll
            for (int ni = 0; ni < 8; ++ni)
                wqv[ni] = wq[(size_t)b * T_DIM + sh * 256 + wn * 128 + ni * 16 + fr];
            #pragma unroll
            for (int mi = 0; mi < 4; ++mi) {
                #pragma unroll
                for (int rg = 0; rg < 4; ++rg) {
                    float part = 0.f;
                    #pragma unroll
                    for (int ni = 0; ni < 8; ++ni)
                        part += vev[ni] * ftanh(wqv[ni] + acc[mi][ni][rg]);
                    part += __shfl_xor(part, 1);
                    part += __shfl_xor(part, 2);
                    part += __shfl_xor(part, 4);
                    part += __shfl_xor(part, 8);
                    if (fr == 0)
                        atomicAdd(&sc[wm * 64 + mi * 16 + 4 * g + rg], part);
                    // exactly 2 adds per slot (wn=0,1): commutative -> deterministic
                }
            }
            __syncthreads();   // all atomics visible
            if (tid < 128)
                partial[((size_t)b * 2 + sh) * N_DIM + nb * 128 + tid] = sc[tid];
            if (t < 63) {
                if (tid < 128) sc[tid] = 0.f;   // safe: next atomics after >=1 barrier
                #pragma unroll
                for (int i = 0; i < 4; ++i)
                    #pragma unroll
                    for (int j = 0; j < 8; ++j)
                        acc[i][j] = zero;
            }
        }
    }
}

// ---------------- softmax over n (sums the 2 s-half partials) ----------------
__global__ __launch_bounds__(512) void softmax_kernel(
    const float* __restrict__ partial, float* __restrict__ out)
{
    const int b = blockIdx.x;
    const int n = threadIdx.x;
    const float* p = partial + (size_t)b * 2 * N_DIM;
    float s = p[n] + p[N_DIM + n];

    float m = s;
    #pragma unroll
    for (int off = 1; off < 64; off <<= 1)
        m = fmaxf(m, __shfl_xor(m, off));
    __shared__ float red[8];
    const int wv = n >> 6;
    if ((n & 63) == 0) red[wv] = m;
    __syncthreads();
    float bm = red[0];
    #pragma unroll
    for (int i = 1; i < 8; ++i) bm = fmaxf(bm, red[i]);

    float e = expf(s - bm);
    float t = e;
    #pragma unroll
    for (int off = 1; off < 64; off <<= 1)
        t += __shfl_xor(t, off);
    __syncthreads();
    if ((n & 63) == 0) red[wv] = t;
    __syncthreads();
    float tot = 0.f;
    #pragma unroll
    for (int i = 0; i < 8; ++i) tot += red[i];

    out[(size_t)b * N_DIM + n] = e / tot;
}

extern "C" void kernel_launch(void* const* d_in, const int* in_sizes, int n_in,
                              void* d_out, int out_size, void* d_ws, size_t ws_size,
                              hipStream_t stream) {
    const float* h_t  = (const float*)d_in[0];
    const float* s_t  = (const float*)d_in[1];
    const float* data = (const float*)d_in[2];
    const float* W_e  = (const float*)d_in[3];
    const float* U_e  = (const float*)d_in[4];
    const float* v_e  = (const float*)d_in[5];
    float* out = (float*)d_out;

    const size_t wq_elems      = (size_t)B_DIM * T_DIM;         // f32
    const size_t partial_elems = (size_t)B_DIM * 2 * N_DIM;     // f32
    const size_t u_elems       = (size_t)T_DIM * T_DIM;         // bf16

    float* wq      = (float*)d_ws;
    float* partial = wq + wq_elems;
    __bf16* Uh     = (__bf16*)(partial + partial_elems);

    wq_kernel<<<B_DIM, 256, 0, stream>>>(h_t, s_t, W_e, wq);
    uconv_kernel<<<(int)(u_elems / 512), 256, 0, stream>>>(U_e, Uh);
    fused8_kernel<<<512, 256, 0, stream>>>(data, Uh, v_e, wq, partial);
    softmax_kernel<<<B_DIM, 512, 0, stream>>>(partial, out);
}

// Round 11
// 163.472 us; speedup vs baseline: 1.3915x; 1.0073x over previous
//
#include <hip/hip_runtime.h>
#include <hip/hip_bf16.h>
#include <cmath>

#define T_DIM 512
#define N_DIM 512
#define M_DIM 256
#define B_DIM 256

typedef __bf16 bf16x8 __attribute__((ext_vector_type(8)));
typedef float  f32x4  __attribute__((ext_vector_type(4)));
typedef unsigned int u32;

__device__ __forceinline__ void gload16(const __bf16* g, __bf16* l) {
    __builtin_amdgcn_global_load_lds(
        (const __attribute__((address_space(1))) void*)g,
        (__attribute__((address_space(3))) void*)l, 16, 0, 0);
}

// bank-spread key (R9/R10-proven)
__device__ __forceinline__ int bkey(int r) { return ((r >> 3) ^ (r >> 1)) & 3; }

// fast tanh: 1 - 2/(e^{2x}+1); exact at +-inf, ~1e-6 abs error (R10-validated)
__device__ __forceinline__ float ftanh(float x) {
    return 1.f - 2.f / (__expf(2.f * x) + 1.f);
}

// ---------------- precompute: U_e -> bf16 ----------------
__global__ __launch_bounds__(256) void uconv_kernel(
    const float* __restrict__ U, __bf16* __restrict__ Uh)
{
    const int i = (blockIdx.x * 256 + threadIdx.x) * 2;
    float2 v = *(const float2*)(U + i);
    Uh[i]   = (__bf16)v.x;
    Uh[i+1] = (__bf16)v.y;
}

// ---------------- wq[b,t] = concat(h,s) . W_e[t,:] ----------------
__global__ __launch_bounds__(256) void wq_kernel(
    const float* __restrict__ h_t, const float* __restrict__ s_t,
    const float* __restrict__ W_e, float* __restrict__ wq)
{
    __shared__ float q[2 * M_DIM];
    const int b = blockIdx.x;
    const int tid = threadIdx.x;
    q[tid]         = h_t[(size_t)b * M_DIM + tid];
    q[M_DIM + tid] = s_t[(size_t)b * M_DIM + tid];
    __syncthreads();
    for (int tt = tid; tt < T_DIM; tt += 256) {
        const float4* wrow = (const float4*)(W_e + (size_t)tt * (2 * M_DIM));
        float acc = 0.f;
        #pragma unroll 4
        for (int k4 = 0; k4 < (2 * M_DIM) / 4; ++k4) {
            float4 w = wrow[k4];
            acc += q[4*k4+0] * w.x + q[4*k4+1] * w.y
                 + q[4*k4+2] * w.z + q[4*k4+3] * w.w;
        }
        wq[(size_t)b * T_DIM + tt] = acc;
    }
}

// ---------------- fused: merged-sh 8-wave wg, 4 panels, flat 64-step loop ----------------
// wg = (bgrp, nb): tile 128 n x 512 s (FULL s), K = 512 t, 4 batches back-to-back.
// One A-transpose serves all 512 s-columns (halves cvt/pa work per FLOP vs R10).
// Deterministic epilogue: per-wn LDS slices + fixed-order 4-term sum (no atomics).
__global__ __launch_bounds__(512, 2) void fused9_kernel(
    const float* __restrict__ data, const __bf16* __restrict__ Uh,
    const float* __restrict__ v_e, const float* __restrict__ wq,
    float* __restrict__ scores)
{
    __shared__ __align__(16) __bf16 As[2][128 * 32];   // 16 KB  [n][t-slots]
    __shared__ __align__(16) __bf16 Bs[2][512 * 32];   // 64 KB  [s][t-slots]
    __shared__ float sc2[4][128];                      // per-wn partial slices

    const int wg   = blockIdx.x;
    const int bgrp = wg >> 2;            // 0..63
    const int nb   = wg & 3;

    const int tid  = threadIdx.x;        // 0..511
    const int lane = tid & 63;
    const int wid  = tid >> 6;           // 0..7
    const int wm   = wid >> 2;           // n-half (0..1)
    const int wn   = wid & 3;            // s-quarter (0..3)

    f32x4 acc[4][8];
    const f32x4 zero = {0.f, 0.f, 0.f, 0.f};
    #pragma unroll
    for (int i = 0; i < 4; ++i)
        #pragma unroll
        for (int j = 0; j < 8; ++j)
            acc[i][j] = zero;

    // A staging: rp = t-pair (0..15), nq = n-quad (0..31); 32 lanes = 512 B coalesced
    const int rp = tid >> 5;
    const int nq = tid & 31;
    const int n0 = nq * 4;

    // A source: rows contiguous across panels (b = bgrp*4 + row/512)
    const float* Apan = data + ((size_t)bgrp * 4 * T_DIM) * N_DIM + nb * 128 + n0;

    // B staging: 4 x gload_lds, rows r0+128i, source-side chunk swizzle (R9)
    const __bf16* Bb = Uh;               // full U (512 s rows)
    const int r0   = tid >> 2;           // 0..127
    const int keyB = bkey(r0);           // invariant under +128i
    const int ce   = (((tid & 3) ^ keyB) * 8);

    const int fr = lane & 15;
    const int kb = (lane >> 4) * 8;

    int aoff[4];
    #pragma unroll
    for (int mi = 0; mi < 4; ++mi) {
        const int row = wm * 64 + mi * 16 + fr;
        aoff[mi] = row * 32 + (kb ^ (bkey(row) << 3));
    }
    int boff[8];
    #pragma unroll
    for (int ni = 0; ni < 8; ++ni) {
        const int row = wn * 128 + ni * 16 + fr;
        boff[ni] = row * 32 + (kb ^ (bkey(row) << 3));
    }

    // epilogue constants
    float vev[8];
    #pragma unroll
    for (int ni = 0; ni < 8; ++ni)
        vev[ni] = v_e[wn * 128 + ni * 16 + fr];
    const int g = lane >> 4;

    // ---- prologue: tile 0 -> buf 0; pa <- tile 1
    float4 pa0, pa1;
    {
        const float* s0 = Apan + (size_t)(2 * rp) * N_DIM;
        pa0 = *(const float4*)s0;
        pa1 = *(const float4*)(s0 + N_DIM);
    }
    #pragma unroll
    for (int i = 0; i < 4; ++i)
        gload16(Bb + (size_t)(i * 128 + r0) * T_DIM + ce,
                &Bs[0][0] + (size_t)i * 128 * 32 + tid * 8);
    {
        u32* As32 = (u32*)As[0];
        const float lo_[4] = {pa0.x, pa0.y, pa0.z, pa0.w};
        const float hi_[4] = {pa1.x, pa1.y, pa1.z, pa1.w};
        #pragma unroll
        for (int j = 0; j < 4; ++j) {
            __bf16 l = (__bf16)lo_[j];
            __bf16 h = (__bf16)hi_[j];
            u32 w = ((u32)__builtin_bit_cast(unsigned short, h) << 16)
                  |  (u32)__builtin_bit_cast(unsigned short, l);
            const int key = bkey(n0 + j);
            As32[(n0 + j) * 16 + (rp ^ (key << 2))] = w;
        }
    }
    {
        const float* sn = Apan + (size_t)(32 + 2 * rp) * N_DIM;
        pa0 = *(const float4*)sn;
        pa1 = *(const float4*)(sn + N_DIM);
    }
    __syncthreads();

    // ---- flat 64-step loop (4 panels x 16 K-steps)
    for (int t = 0; t < 64; ++t) {
        const int cur = t & 1;

        bf16x8 a[4], bv[8];
        #pragma unroll
        for (int mi = 0; mi < 4; ++mi)
            a[mi] = *(const bf16x8*)&As[cur][aoff[mi]];
        #pragma unroll
        for (int ni = 0; ni < 8; ++ni)
            bv[ni] = *(const bf16x8*)&Bs[cur][boff[ni]];

        if (t < 63) {
            const int nxt = cur ^ 1;
            const int kcol = ((t + 1) & 15) << 5;   // B wraps every panel
            #pragma unroll
            for (int i = 0; i < 4; ++i)
                gload16(Bb + (size_t)(i * 128 + r0) * T_DIM + kcol + ce,
                        &Bs[nxt][0] + (size_t)i * 128 * 32 + tid * 8);
            u32* As32 = (u32*)As[nxt];
            const float lo_[4] = {pa0.x, pa0.y, pa0.z, pa0.w};
            const float hi_[4] = {pa1.x, pa1.y, pa1.z, pa1.w};
            #pragma unroll
            for (int j = 0; j < 4; ++j) {
                __bf16 l = (__bf16)lo_[j];
                __bf16 h = (__bf16)hi_[j];
                u32 w = ((u32)__builtin_bit_cast(unsigned short, h) << 16)
                      |  (u32)__builtin_bit_cast(unsigned short, l);
                const int key = bkey(n0 + j);
                As32[(n0 + j) * 16 + (rp ^ (key << 2))] = w;
            }
            if (t < 62) {
                const float* sn = Apan + (size_t)(32 * (t + 2) + 2 * rp) * N_DIM;
                pa0 = *(const float4*)sn;
                pa1 = *(const float4*)(sn + N_DIM);
            }
        }

        __builtin_amdgcn_s_setprio(1);
        #pragma unroll
        for (int mi = 0; mi < 4; ++mi)
            #pragma unroll
            for (int ni = 0; ni < 8; ++ni)
                acc[mi][ni] = __builtin_amdgcn_mfma_f32_16x16x32_bf16(a[mi], bv[ni], acc[mi][ni], 0, 0, 0);
        __builtin_amdgcn_s_setprio(0);

        __syncthreads();   // buf[cur^1] ready for next step

        // ---- per-panel epilogue (uniform branch)
        if ((t & 15) == 15) {
            const int b = bgrp * 4 + (t >> 4);
            float wqv[8];
            #pragma unroll
            for (int ni = 0; ni < 8; ++ni)
                wqv[ni] = wq[(size_t)b * T_DIM + wn * 128 + ni * 16 + fr];
            #pragma unroll
            for (int mi = 0; mi < 4; ++mi) {
                #pragma unroll
                for (int rg = 0; rg < 4; ++rg) {
                    float part = 0.f;
                    #pragma unroll
                    for (int ni = 0; ni < 8; ++ni)
                        part += vev[ni] * ftanh(wqv[ni] + acc[mi][ni][rg]);
                    part += __shfl_xor(part, 1);
                    part += __shfl_xor(part, 2);
                    part += __shfl_xor(part, 4);
                    part += __shfl_xor(part, 8);
                    if (fr == 0)
                        sc2[wn][wm * 64 + mi * 16 + 4 * g + rg] = part;  // plain store
                }
            }
            __syncthreads();   // sc2 slices complete
            if (tid < 128) {
                // fixed-order 4-term sum -> fully deterministic
                const float s = sc2[0][tid] + sc2[1][tid] + sc2[2][tid] + sc2[3][tid];
                scores[(size_t)b * N_DIM + nb * 128 + tid] = s;
            }
            if (t < 63) {
                #pragma unroll
                for (int i = 0; i < 4; ++i)
                    #pragma unroll
                    for (int j = 0; j < 8; ++j)
                        acc[i][j] = zero;
            }
        }
    }
}

// ---------------- softmax over n ----------------
__global__ __launch_bounds__(512) void softmax_kernel(
    const float* __restrict__ scores, float* __restrict__ out)
{
    const int b = blockIdx.x;
    const int n = threadIdx.x;
    float s = scores[(size_t)b * N_DIM + n];

    float m = s;
    #pragma unroll
    for (int off = 1; off < 64; off <<= 1)
        m = fmaxf(m, __shfl_xor(m, off));
    __shared__ float red[8];
    const int wv = n >> 6;
    if ((n & 63) == 0) red[wv] = m;
    __syncthreads();
    float bm = red[0];
    #pragma unroll
    for (int i = 1; i < 8; ++i) bm = fmaxf(bm, red[i]);

    float e = expf(s - bm);
    float t = e;
    #pragma unroll
    for (int off = 1; off < 64; off <<= 1)
        t += __shfl_xor(t, off);
    __syncthreads();
    if ((n & 63) == 0) red[wv] = t;
    __syncthreads();
    float tot = 0.f;
    #pragma unroll
    for (int i = 0; i < 8; ++i) tot += red[i];

    out[(size_t)b * N_DIM + n] = e / tot;
}

extern "C" void kernel_launch(void* const* d_in, const int* in_sizes, int n_in,
                              void* d_out, int out_size, void* d_ws, size_t ws_size,
                              hipStream_t stream) {
    const float* h_t  = (const float*)d_in[0];
    const float* s_t  = (const float*)d_in[1];
    const float* data = (const float*)d_in[2];
    const float* W_e  = (const float*)d_in[3];
    const float* U_e  = (const float*)d_in[4];
    const float* v_e  = (const float*)d_in[5];
    float* out = (float*)d_out;

    const size_t wq_elems     = (size_t)B_DIM * T_DIM;      // f32
    const size_t score_elems  = (size_t)B_DIM * N_DIM;      // f32
    const size_t u_elems      = (size_t)T_DIM * T_DIM;      // bf16

    float* wq      = (float*)d_ws;
    float* scores  = wq + wq_elems;
    __bf16* Uh     = (__bf16*)(scores + score_elems);

    wq_kernel<<<B_DIM, 256, 0, stream>>>(h_t, s_t, W_e, wq);
    uconv_kernel<<<(int)(u_elems / 512), 256, 0, stream>>>(U_e, Uh);
    fused9_kernel<<<256, 512, 0, stream>>>(data, Uh, v_e, wq, scores);
    softmax_kernel<<<B_DIM, 512, 0, stream>>>(scores, out);
}